// Round 15
// baseline (140.406 us; speedup 1.0000x reference)
//
#include <hip/hip_runtime.h>
#include <math.h>

#define BT 32768   // B*T tokens
#define DD 1024    // feature dim
#define NN 512     // buffer slots
#define PP 1024    // partial-sum blocks

typedef float v4f __attribute__((ext_vector_type(4)));

__device__ __forceinline__ float fast_gelu(float x) {
    // 0.5*x*(1+tanh(c*(x+0.044715 x^3))), tanh(u) = 1 - 2/(exp(2u)+1)
    float u = 0.7978845608028654f * (x + 0.044715f * x * x * x);
    float e = __expf(2.0f * u);
    float t = 1.0f - __fdividef(2.0f, e + 1.0f);
    return 0.5f * x * (1.0f + t);
}

__device__ __forceinline__ v4f gelu4(v4f v, float g) {
    v4f r;
    r.x = fast_gelu(v.x) * g;
    r.y = fast_gelu(v.y) * g;
    r.z = fast_gelu(v.z) * g;
    r.w = fast_gelu(v.w) * g;
    return r;
}

// Pass 1a: per-column partial sums of gelu(x). part[PP][DD]  (unchanged)
__global__ __launch_bounds__(256) void k_partial(const v4f* __restrict__ x4,
                                                 v4f* __restrict__ part) {
    int t = threadIdx.x;  // 0..255 -> cols 4t..4t+3
    v4f acc = {0.f, 0.f, 0.f, 0.f};
    for (int row = blockIdx.x; row < BT; row += PP) {
        v4f v = x4[row * (DD / 4) + t];
        acc.x += fast_gelu(v.x);
        acc.y += fast_gelu(v.y);
        acc.z += fast_gelu(v.z);
        acc.w += fast_gelu(v.w);
    }
    part[blockIdx.x * (DD / 4) + t] = acc;
}

// Pass 1b: reduce PP partial rows -> 16 rows. 64 blocks x 256 thr.  (unchanged)
__global__ __launch_bounds__(256) void k_reduce1(const float* __restrict__ part,
                                                 float* __restrict__ part2) {
    int g = blockIdx.x * 256 + threadIdx.x;  // 0..16383
    int col = g & (DD - 1);
    int chunk = g >> 10;  // 0..15
    float s = 0.f;
    int r0 = chunk * (PP / 16);
    for (int r = r0; r < r0 + PP / 16; ++r) s += part[r * DD + col];
    part2[chunk * DD + col] = s;
}

// sims: dot[n] = buf[n].m ; sq[n] = ||buf[n]||^2, m on the fly from part2.  (unchanged)
__global__ __launch_bounds__(256) void k_sims(const v4f* __restrict__ buf4,
                                              const float* __restrict__ part2,
                                              float* __restrict__ dot,
                                              float* __restrict__ sq) {
    int n = blockIdx.x;
    int t = threadIdx.x;
    v4f b = buf4[n * (DD / 4) + t];
    float s0 = 0, s1 = 0, s2 = 0, s3 = 0;
    for (int r = 0; r < 16; ++r) {
        v4f p = ((const v4f*)(part2 + r * DD))[t];
        s0 += p.x; s1 += p.y; s2 += p.z; s3 += p.w;
    }
    const float inv = 1.0f / 32768.0f;
    float d = b.x * (s0 * inv) + b.y * (s1 * inv) + b.z * (s2 * inv) + b.w * (s3 * inv);
    float q = b.x * b.x + b.y * b.y + b.z * b.z + b.w * b.w;
    __shared__ float rd[256], rq[256];
    rd[t] = d;
    rq[t] = q;
    __syncthreads();
    for (int st = 128; st > 0; st >>= 1) {
        if (t < st) { rd[t] += rd[t + st]; rq[t] += rq[t + st]; }
        __syncthreads();
    }
    if (t == 0) { dot[n] = rd[0]; sq[n] = rq[0]; }
}

// state: nm from part2, argmax (first-index tie-break), gate, small outputs.  (unchanged)
__global__ __launch_bounds__(512) void k_state(const float* __restrict__ part2,
                                               const float* __restrict__ dot,
                                               const float* __restrict__ sq,
                                               const float* __restrict__ depl,
                                               const int* __restrict__ hits,
                                               const int* __restrict__ mask,   // int32 on device
                                               const float* __restrict__ logk_p,
                                               const float* __restrict__ loglam_p,
                                               const int* __restrict__ ptr_p,
                                               float* __restrict__ out_depl,
                                               float* __restrict__ out_hits,
                                               float* __restrict__ out_mask,
                                               float* __restrict__ gate_p,
                                               float* __restrict__ nm_out) {
    int n = threadIdx.x;
    const float inv = 1.0f / 32768.0f;
    float sa = 0, sb = 0;
    for (int r = 0; r < 16; ++r) {
        sa += part2[r * DD + n];
        sb += part2[r * DD + n + 512];
    }
    float ma = sa * inv, mb = sb * inv;
    __shared__ float red[512];
    red[n] = ma * ma + mb * mb;
    __syncthreads();
    for (int st = 256; st > 0; st >>= 1) {
        if (n < st) red[n] += red[n + st];
        __syncthreads();
    }
    float nm = fmaxf(sqrtf(red[0]), 1e-12f);
    if (n == 0) nm_out[0] = sqrtf(red[0]);
    __syncthreads();

    float nb = fmaxf(sqrtf(sq[n]), 1e-12f);
    bool mk = mask[n] != 0;
    float sim = mk ? dot[n] / (nb * nm) : -1.0f;

    __shared__ float ssim[512];
    __shared__ int sidx[512];
    ssim[n] = sim;
    sidx[n] = n;
    __syncthreads();
    for (int st = 256; st > 0; st >>= 1) {
        if (n < st) {
            float s2 = ssim[n + st];
            int i2 = sidx[n + st];
            if (s2 > ssim[n] || (s2 == ssim[n] && i2 < sidx[n])) {
                ssim[n] = s2;
                sidx[n] = i2;
            }
        }
        __syncthreads();
    }

    __shared__ int s_near, s_fired;
    if (n == 0) {
        int nearest = sidx[0];
        float msim = ssim[0];
        float k_depl = fminf(fmaxf(expf(logk_p[0]), 0.1f), 5.0f);
        float lam = fminf(fmaxf(expf(loglam_p[0]), 0.1f), 3.0f);
        float g = expf(-k_depl * (1.0f - depl[nearest]) - lam * (float)hits[nearest]);
        s_near = nearest;
        s_fired = (msim > 0.85f) ? 1 : 0;
        gate_p[0] = g;
    }
    __syncthreads();

    int ptr = ptr_p[0];
    float nd = depl[n];
    int nh = hits[n];
    float nmsk = mk ? 1.0f : 0.0f;
    if (n == s_near && s_fired) { nd *= 0.5f; nh += 1; }
    if (n == ptr) { nd = 1.0f; nh = 0; nmsk = 1.0f; }
    out_depl[n] = nd;
    out_hits[n] = (float)nh;
    out_mask[n] = nmsk;
}

// R15 PROBE: exact copy of k_outbuf's gelu branch (2048 blocks). Writes the
// y-region of out, which the real k_outbuf then fully overwrites — measures
// one isolated gelu-pass execution as Δdur vs R14.
__global__ __launch_bounds__(256) void k_outprobe(const v4f* __restrict__ x4,
                                                  v4f* __restrict__ o4,
                                                  const float* __restrict__ gate_p) {
    int t = threadIdx.x;
    float g = gate_p[0];
    int base = blockIdx.x * 4096 + t;
    #pragma unroll
    for (int k = 0; k < 4; ++k) {
        int i0 = base + (4 * k + 0) * 256;
        int i1 = base + (4 * k + 1) * 256;
        int i2 = base + (4 * k + 2) * 256;
        int i3 = base + (4 * k + 3) * 256;
        v4f a0 = x4[i0];
        v4f a1 = x4[i1];
        v4f a2 = x4[i2];
        v4f a3 = x4[i3];
        v4f r0 = gelu4(a0, g);
        v4f r1 = gelu4(a1, g);
        v4f r2 = gelu4(a2, g);
        v4f r3 = gelu4(a3, g);
        __builtin_nontemporal_store(r0, &o4[i0]);
        __builtin_nontemporal_store(r1, &o4[i1]);
        __builtin_nontemporal_store(r2, &o4[i2]);
        __builtin_nontemporal_store(r3, &o4[i3]);
    }
}

// Pass 2 (real): gelu blocks + buf-copy blocks.  (R14 form, unchanged)
__global__ __launch_bounds__(256) void k_outbuf(const v4f* __restrict__ x4,
                                                v4f* __restrict__ o4,
                                                const v4f* __restrict__ buf4,
                                                const float* __restrict__ part2,
                                                const float* __restrict__ nm_p,
                                                v4f* __restrict__ ob4,
                                                const float* __restrict__ gate_p,
                                                const int* __restrict__ ptrp) {
    int t = threadIdx.x;
    if (blockIdx.x < 2048) {
        float g = gate_p[0];
        int base = blockIdx.x * 4096 + t;  // block covers contiguous 64 KB
        #pragma unroll
        for (int k = 0; k < 4; ++k) {
            int i0 = base + (4 * k + 0) * 256;
            int i1 = base + (4 * k + 1) * 256;
            int i2 = base + (4 * k + 2) * 256;
            int i3 = base + (4 * k + 3) * 256;
            v4f a0 = x4[i0];
            v4f a1 = x4[i1];
            v4f a2 = x4[i2];
            v4f a3 = x4[i3];
            v4f r0 = gelu4(a0, g);
            v4f r1 = gelu4(a1, g);
            v4f r2 = gelu4(a2, g);
            v4f r3 = gelu4(a3, g);
            __builtin_nontemporal_store(r0, &o4[i0]);
            __builtin_nontemporal_store(r1, &o4[i1]);
            __builtin_nontemporal_store(r2, &o4[i2]);
            __builtin_nontemporal_store(r3, &o4[i3]);
        }
    } else {
        int b2 = blockIdx.x - 2048;  // 0..31
        int ptr = ptrp[0];
        for (int k = 0; k < 16; ++k) {
            int i = b2 * 4096 + k * 256 + t;  // 131072 float4 total
            int row = i >> 8;  // 256 float4 per row
            v4f v;
            if (row == ptr) {
                int c4 = i & 255;
                float s0 = 0, s1 = 0, s2 = 0, s3 = 0;
                for (int r = 0; r < 16; ++r) {
                    v4f p = ((const v4f*)(part2 + r * DD))[c4];
                    s0 += p.x; s1 += p.y; s2 += p.z; s3 += p.w;
                }
                const float inv = 1.0f / 32768.0f;
                float den = fmaxf(nm_p[0], 1e-12f);
                v.x = s0 * inv / den;
                v.y = s1 * inv / den;
                v.z = s2 * inv / den;
                v.w = s3 * inv / den;
            } else {
                v = buf4[i];
            }
            ob4[i] = v;
        }
    }
}

extern "C" void kernel_launch(void* const* d_in, const int* in_sizes, int n_in,
                              void* d_out, int out_size, void* d_ws, size_t ws_size,
                              hipStream_t stream) {
    const float* x = (const float*)d_in[0];
    const float* log_k = (const float*)d_in[1];
    const float* log_lambda = (const float*)d_in[2];
    const float* buf = (const float*)d_in[3];
    const float* depl = (const float*)d_in[4];
    const int* hits = (const int*)d_in[5];
    const int* mask = (const int*)d_in[6];  // bool pushed as int32
    const int* ptr = (const int*)d_in[7];

    float* out = (float*)d_out;
    float* out_buf = out + 33554432;      // N*D
    float* out_depl = out_buf + NN * DD;  // 512
    float* out_hits = out_depl + NN;      // 512
    float* out_mask = out_hits + NN;      // 512

    // small scratch in ws
    float* wsf = (float*)d_ws;
    float* part2 = wsf;              // 16*1024 (64 KB)
    float* nm = wsf + 16384;         // 1
    float* gate = wsf + 16385;       // 1
    float* dot = wsf + 16400;        // 512
    float* sq = wsf + 16912;         // 512

    // big partial-sum scratch in the output region (4 MB), consumed before k_outbuf overwrites
    float* part = out;

    k_partial<<<dim3(PP), dim3(256), 0, stream>>>((const v4f*)x, (v4f*)part);
    k_reduce1<<<dim3(64), dim3(256), 0, stream>>>(part, part2);
    k_sims<<<dim3(NN), dim3(256), 0, stream>>>((const v4f*)buf, part2, dot, sq);
    k_state<<<dim3(1), dim3(512), 0, stream>>>(part2, dot, sq, depl, hits, mask,
                                               log_k, log_lambda, ptr,
                                               out_depl, out_hits, out_mask, gate, nm);
    k_outprobe<<<dim3(2048), dim3(256), 0, stream>>>((const v4f*)x, (v4f*)out, gate);  // R15 probe
    k_outbuf<<<dim3(2080), dim3(256), 0, stream>>>((const v4f*)x, (v4f*)out,
                                                   (const v4f*)buf, part2, nm,
                                                   (v4f*)out_buf, gate, ptr);
}

// Round 16
// 116.240 us; speedup vs baseline: 1.2079x; 1.2079x over previous
//
#include <hip/hip_runtime.h>
#include <math.h>

#define BT 32768   // B*T tokens
#define DD 1024    // feature dim
#define NN 512     // buffer slots
#define PP 1024    // partial-sum blocks

typedef float v4f __attribute__((ext_vector_type(4)));

__device__ __forceinline__ float fast_gelu(float x) {
    float u = 0.7978845608028654f * (x + 0.044715f * x * x * x);
    float e = __expf(2.0f * u);
    float t = 1.0f - __fdividef(2.0f, e + 1.0f);
    return 0.5f * x * (1.0f + t);
}

__device__ __forceinline__ v4f gelu4(v4f v, float g) {
    v4f r;
    r.x = fast_gelu(v.x) * g;
    r.y = fast_gelu(v.y) * g;
    r.z = fast_gelu(v.z) * g;
    r.w = fast_gelu(v.w) * g;
    return r;
}

// Pass 1a  (unchanged, R9-proven)
__global__ __launch_bounds__(256) void k_partial(const v4f* __restrict__ x4,
                                                 v4f* __restrict__ part) {
    int t = threadIdx.x;
    v4f acc = {0.f, 0.f, 0.f, 0.f};
    for (int row = blockIdx.x; row < BT; row += PP) {
        v4f v = x4[row * (DD / 4) + t];
        acc.x += fast_gelu(v.x);
        acc.y += fast_gelu(v.y);
        acc.z += fast_gelu(v.z);
        acc.w += fast_gelu(v.w);
    }
    part[blockIdx.x * (DD / 4) + t] = acc;
}

// Pass 1b  (unchanged)
__global__ __launch_bounds__(256) void k_reduce1(const float* __restrict__ part,
                                                 float* __restrict__ part2) {
    int g = blockIdx.x * 256 + threadIdx.x;
    int col = g & (DD - 1);
    int chunk = g >> 10;
    float s = 0.f;
    int r0 = chunk * (PP / 16);
    for (int r = r0; r < r0 + PP / 16; ++r) s += part[r * DD + col];
    part2[chunk * DD + col] = s;
}

// sims  (unchanged)
__global__ __launch_bounds__(256) void k_sims(const v4f* __restrict__ buf4,
                                              const float* __restrict__ part2,
                                              float* __restrict__ dot,
                                              float* __restrict__ sq) {
    int n = blockIdx.x;
    int t = threadIdx.x;
    v4f b = buf4[n * (DD / 4) + t];
    float s0 = 0, s1 = 0, s2 = 0, s3 = 0;
    for (int r = 0; r < 16; ++r) {
        v4f p = ((const v4f*)(part2 + r * DD))[t];
        s0 += p.x; s1 += p.y; s2 += p.z; s3 += p.w;
    }
    const float inv = 1.0f / 32768.0f;
    float d = b.x * (s0 * inv) + b.y * (s1 * inv) + b.z * (s2 * inv) + b.w * (s3 * inv);
    float q = b.x * b.x + b.y * b.y + b.z * b.z + b.w * b.w;
    __shared__ float rd[256], rq[256];
    rd[t] = d;
    rq[t] = q;
    __syncthreads();
    for (int st = 128; st > 0; st >>= 1) {
        if (t < st) { rd[t] += rd[t + st]; rq[t] += rq[t + st]; }
        __syncthreads();
    }
    if (t == 0) { dot[n] = rd[0]; sq[n] = rq[0]; }
}

// state  (unchanged)
__global__ __launch_bounds__(512) void k_state(const float* __restrict__ part2,
                                               const float* __restrict__ dot,
                                               const float* __restrict__ sq,
                                               const float* __restrict__ depl,
                                               const int* __restrict__ hits,
                                               const int* __restrict__ mask,
                                               const float* __restrict__ logk_p,
                                               const float* __restrict__ loglam_p,
                                               const int* __restrict__ ptr_p,
                                               float* __restrict__ out_depl,
                                               float* __restrict__ out_hits,
                                               float* __restrict__ out_mask,
                                               float* __restrict__ gate_p,
                                               float* __restrict__ nm_out) {
    int n = threadIdx.x;
    const float inv = 1.0f / 32768.0f;
    float sa = 0, sb = 0;
    for (int r = 0; r < 16; ++r) {
        sa += part2[r * DD + n];
        sb += part2[r * DD + n + 512];
    }
    float ma = sa * inv, mb = sb * inv;
    __shared__ float red[512];
    red[n] = ma * ma + mb * mb;
    __syncthreads();
    for (int st = 256; st > 0; st >>= 1) {
        if (n < st) red[n] += red[n + st];
        __syncthreads();
    }
    float nm = fmaxf(sqrtf(red[0]), 1e-12f);
    if (n == 0) nm_out[0] = sqrtf(red[0]);
    __syncthreads();

    float nb = fmaxf(sqrtf(sq[n]), 1e-12f);
    bool mk = mask[n] != 0;
    float sim = mk ? dot[n] / (nb * nm) : -1.0f;

    __shared__ float ssim[512];
    __shared__ int sidx[512];
    ssim[n] = sim;
    sidx[n] = n;
    __syncthreads();
    for (int st = 256; st > 0; st >>= 1) {
        if (n < st) {
            float s2 = ssim[n + st];
            int i2 = sidx[n + st];
            if (s2 > ssim[n] || (s2 == ssim[n] && i2 < sidx[n])) {
                ssim[n] = s2;
                sidx[n] = i2;
            }
        }
        __syncthreads();
    }

    __shared__ int s_near, s_fired;
    if (n == 0) {
        int nearest = sidx[0];
        float msim = ssim[0];
        float k_depl = fminf(fmaxf(expf(logk_p[0]), 0.1f), 5.0f);
        float lam = fminf(fmaxf(expf(loglam_p[0]), 0.1f), 3.0f);
        float g = expf(-k_depl * (1.0f - depl[nearest]) - lam * (float)hits[nearest]);
        s_near = nearest;
        s_fired = (msim > 0.85f) ? 1 : 0;
        gate_p[0] = g;
    }
    __syncthreads();

    int ptr = ptr_p[0];
    float nd = depl[n];
    int nh = hits[n];
    float nmsk = mk ? 1.0f : 0.0f;
    if (n == s_near && s_fired) { nd *= 0.5f; nh += 1; }
    if (n == ptr) { nd = 1.0f; nh = 0; nmsk = 1.0f; }
    out_depl[n] = nd;
    out_hits[n] = (float)nh;
    out_mask[n] = nmsk;
}

// Pass 2  (R14 form, unchanged)
__global__ __launch_bounds__(256) void k_outbuf(const v4f* __restrict__ x4,
                                                v4f* __restrict__ o4,
                                                const v4f* __restrict__ buf4,
                                                const float* __restrict__ part2,
                                                const float* __restrict__ nm_p,
                                                v4f* __restrict__ ob4,
                                                const float* __restrict__ gate_p,
                                                const int* __restrict__ ptrp) {
    int t = threadIdx.x;
    if (blockIdx.x < 2048) {
        float g = gate_p[0];
        int base = blockIdx.x * 4096 + t;
        #pragma unroll
        for (int k = 0; k < 4; ++k) {
            int i0 = base + (4 * k + 0) * 256;
            int i1 = base + (4 * k + 1) * 256;
            int i2 = base + (4 * k + 2) * 256;
            int i3 = base + (4 * k + 3) * 256;
            v4f a0 = x4[i0];
            v4f a1 = x4[i1];
            v4f a2 = x4[i2];
            v4f a3 = x4[i3];
            v4f r0 = gelu4(a0, g);
            v4f r1 = gelu4(a1, g);
            v4f r2 = gelu4(a2, g);
            v4f r3 = gelu4(a3, g);
            __builtin_nontemporal_store(r0, &o4[i0]);
            __builtin_nontemporal_store(r1, &o4[i1]);
            __builtin_nontemporal_store(r2, &o4[i2]);
            __builtin_nontemporal_store(r3, &o4[i3]);
        }
    } else {
        int b2 = blockIdx.x - 2048;
        int ptr = ptrp[0];
        for (int k = 0; k < 16; ++k) {
            int i = b2 * 4096 + k * 256 + t;
            int row = i >> 8;
            v4f v;
            if (row == ptr) {
                int c4 = i & 255;
                float s0 = 0, s1 = 0, s2 = 0, s3 = 0;
                for (int r = 0; r < 16; ++r) {
                    v4f p = ((const v4f*)(part2 + r * DD))[c4];
                    s0 += p.x; s1 += p.y; s2 += p.z; s3 += p.w;
                }
                const float inv = 1.0f / 32768.0f;
                float den = fmaxf(nm_p[0], 1e-12f);
                v.x = s0 * inv / den;
                v.y = s1 * inv / den;
                v.z = s2 * inv / den;
                v.w = s3 * inv / den;
            } else {
                v = buf4[i];
            }
            ob4[i] = v;
        }
    }
}

extern "C" void kernel_launch(void* const* d_in, const int* in_sizes, int n_in,
                              void* d_out, int out_size, void* d_ws, size_t ws_size,
                              hipStream_t stream) {
    const float* x = (const float*)d_in[0];
    const float* log_k = (const float*)d_in[1];
    const float* log_lambda = (const float*)d_in[2];
    const float* buf = (const float*)d_in[3];
    const float* depl = (const float*)d_in[4];
    const int* hits = (const int*)d_in[5];
    const int* mask = (const int*)d_in[6];
    const int* ptr = (const int*)d_in[7];

    float* out = (float*)d_out;
    float* out_buf = out + 33554432;
    float* out_depl = out_buf + NN * DD;
    float* out_hits = out_depl + NN;
    float* out_mask = out_hits + NN;

    // real small scratch in ws
    float* wsf = (float*)d_ws;
    float* part2 = wsf;              // 16*1024
    float* nm = wsf + 16384;
    float* gate = wsf + 16385;
    float* dot = wsf + 16400;        // 512
    float* sq = wsf + 16912;         // 512

    // big scratch + R16 probe-dup outputs live in the out region (overwritten by k_outbuf)
    float* part = out;                      // 4 MB
    float* dup = out + 2097152;             // dup strip @ +8 MB bytes: part2_dup etc.
    float* part2_dup = dup;                 // 16384
    float* nm_dup = dup + 16384;
    float* gate_dup = dup + 16385;
    float* dot_dup = dup + 16400;           // 512
    float* sq_dup = dup + 16912;            // 512
    float* depl_dup = dup + 17424;          // 512
    float* hits_dup = dup + 17936;          // 512
    float* mask_dup = dup + 18448;          // 512

    k_partial<<<dim3(PP), dim3(256), 0, stream>>>((const v4f*)x, (v4f*)part);
    k_reduce1<<<dim3(64), dim3(256), 0, stream>>>(part, part2);
    k_reduce1<<<dim3(64), dim3(256), 0, stream>>>(part, part2_dup);            // probe
    k_sims<<<dim3(NN), dim3(256), 0, stream>>>((const v4f*)buf, part2, dot, sq);
    k_sims<<<dim3(NN), dim3(256), 0, stream>>>((const v4f*)buf, part2, dot_dup, sq_dup);  // probe
    k_state<<<dim3(1), dim3(512), 0, stream>>>(part2, dot, sq, depl, hits, mask,
                                               log_k, log_lambda, ptr,
                                               out_depl, out_hits, out_mask, gate, nm);
    k_state<<<dim3(1), dim3(512), 0, stream>>>(part2, dot, sq, depl, hits, mask,
                                               log_k, log_lambda, ptr,
                                               depl_dup, hits_dup, mask_dup, gate_dup, nm_dup);  // probe
    k_outbuf<<<dim3(2080), dim3(256), 0, stream>>>((const v4f*)x, (v4f*)out,
                                                   (const v4f*)buf, part2, nm,
                                                   (v4f*)out_buf, gate, ptr);
}

// Round 19
// 98.841 us; speedup vs baseline: 1.4205x; 1.1760x over previous
//
#include <hip/hip_runtime.h>
#include <math.h>

#define BT 32768   // B*T tokens
#define DD 1024    // feature dim
#define NN 512     // buffer slots
#define PP 1024    // partial-sum blocks

typedef float v4f __attribute__((ext_vector_type(4)));

__device__ __forceinline__ float fast_gelu(float x) {
    float u = 0.7978845608028654f * (x + 0.044715f * x * x * x);
    float e = __expf(2.0f * u);
    float t = 1.0f - __fdividef(2.0f, e + 1.0f);
    return 0.5f * x * (1.0f + t);
}

__device__ __forceinline__ v4f gelu4(v4f v, float g) {
    v4f r;
    r.x = fast_gelu(v.x) * g;
    r.y = fast_gelu(v.y) * g;
    r.z = fast_gelu(v.z) * g;
    r.w = fast_gelu(v.w) * g;
    return r;
}

// Pass 1a: per-column partial sums of gelu(x). part[PP][DD]
// R17/R18/R19 single variable: explicit 4-deep load clustering (4 back-to-back
// loads -> 16 gelus -> ordered accumulate). Same row order as R9 -> bit-identical part.
__global__ __launch_bounds__(256) void k_partial(const v4f* __restrict__ x4,
                                                 v4f* __restrict__ part) {
    int t = threadIdx.x;  // 0..255 -> cols 4t..4t+3
    v4f acc = {0.f, 0.f, 0.f, 0.f};
    int base = blockIdx.x * (DD / 4) + t;
    const int RS = PP * (DD / 4);  // row stride between this block's rows
    for (int k = 0; k < 8; ++k) {
        v4f a0 = x4[base + (4 * k + 0) * RS];
        v4f a1 = x4[base + (4 * k + 1) * RS];
        v4f a2 = x4[base + (4 * k + 2) * RS];
        v4f a3 = x4[base + (4 * k + 3) * RS];
        acc.x += fast_gelu(a0.x); acc.y += fast_gelu(a0.y);
        acc.z += fast_gelu(a0.z); acc.w += fast_gelu(a0.w);
        acc.x += fast_gelu(a1.x); acc.y += fast_gelu(a1.y);
        acc.z += fast_gelu(a1.z); acc.w += fast_gelu(a1.w);
        acc.x += fast_gelu(a2.x); acc.y += fast_gelu(a2.y);
        acc.z += fast_gelu(a2.z); acc.w += fast_gelu(a2.w);
        acc.x += fast_gelu(a3.x); acc.y += fast_gelu(a3.y);
        acc.z += fast_gelu(a3.z); acc.w += fast_gelu(a3.w);
    }
    part[blockIdx.x * (DD / 4) + t] = acc;
}

// Pass 1b: reduce PP partial rows -> 16 rows. 64 blocks x 256 thr.  (unchanged)
__global__ __launch_bounds__(256) void k_reduce1(const float* __restrict__ part,
                                                 float* __restrict__ part2) {
    int g = blockIdx.x * 256 + threadIdx.x;
    int col = g & (DD - 1);
    int chunk = g >> 10;
    float s = 0.f;
    int r0 = chunk * (PP / 16);
    for (int r = r0; r < r0 + PP / 16; ++r) s += part[r * DD + col];
    part2[chunk * DD + col] = s;
}

// sims  (unchanged)
__global__ __launch_bounds__(256) void k_sims(const v4f* __restrict__ buf4,
                                              const float* __restrict__ part2,
                                              float* __restrict__ dot,
                                              float* __restrict__ sq) {
    int n = blockIdx.x;
    int t = threadIdx.x;
    v4f b = buf4[n * (DD / 4) + t];
    float s0 = 0, s1 = 0, s2 = 0, s3 = 0;
    for (int r = 0; r < 16; ++r) {
        v4f p = ((const v4f*)(part2 + r * DD))[t];
        s0 += p.x; s1 += p.y; s2 += p.z; s3 += p.w;
    }
    const float inv = 1.0f / 32768.0f;
    float d = b.x * (s0 * inv) + b.y * (s1 * inv) + b.z * (s2 * inv) + b.w * (s3 * inv);
    float q = b.x * b.x + b.y * b.y + b.z * b.z + b.w * b.w;
    __shared__ float rd[256], rq[256];
    rd[t] = d;
    rq[t] = q;
    __syncthreads();
    for (int st = 128; st > 0; st >>= 1) {
        if (t < st) { rd[t] += rd[t + st]; rq[t] += rq[t + st]; }
        __syncthreads();
    }
    if (t == 0) { dot[n] = rd[0]; sq[n] = rq[0]; }
}

// state  (unchanged)
__global__ __launch_bounds__(512) void k_state(const float* __restrict__ part2,
                                               const float* __restrict__ dot,
                                               const float* __restrict__ sq,
                                               const float* __restrict__ depl,
                                               const int* __restrict__ hits,
                                               const int* __restrict__ mask,
                                               const float* __restrict__ logk_p,
                                               const float* __restrict__ loglam_p,
                                               const int* __restrict__ ptr_p,
                                               float* __restrict__ out_depl,
                                               float* __restrict__ out_hits,
                                               float* __restrict__ out_mask,
                                               float* __restrict__ gate_p,
                                               float* __restrict__ nm_out) {
    int n = threadIdx.x;
    const float inv = 1.0f / 32768.0f;
    float sa = 0, sb = 0;
    for (int r = 0; r < 16; ++r) {
        sa += part2[r * DD + n];
        sb += part2[r * DD + n + 512];
    }
    float ma = sa * inv, mb = sb * inv;
    __shared__ float red[512];
    red[n] = ma * ma + mb * mb;
    __syncthreads();
    for (int st = 256; st > 0; st >>= 1) {
        if (n < st) red[n] += red[n + st];
        __syncthreads();
    }
    float nm = fmaxf(sqrtf(red[0]), 1e-12f);
    if (n == 0) nm_out[0] = sqrtf(red[0]);
    __syncthreads();

    float nb = fmaxf(sqrtf(sq[n]), 1e-12f);
    bool mk = mask[n] != 0;
    float sim = mk ? dot[n] / (nb * nm) : -1.0f;

    __shared__ float ssim[512];
    __shared__ int sidx[512];
    ssim[n] = sim;
    sidx[n] = n;
    __syncthreads();
    for (int st = 256; st > 0; st >>= 1) {
        if (n < st) {
            float s2 = ssim[n + st];
            int i2 = sidx[n + st];
            if (s2 > ssim[n] || (s2 == ssim[n] && i2 < sidx[n])) {
                ssim[n] = s2;
                sidx[n] = i2;
            }
        }
        __syncthreads();
    }

    __shared__ int s_near, s_fired;
    if (n == 0) {
        int nearest = sidx[0];
        float msim = ssim[0];
        float k_depl = fminf(fmaxf(expf(logk_p[0]), 0.1f), 5.0f);
        float lam = fminf(fmaxf(expf(loglam_p[0]), 0.1f), 3.0f);
        float g = expf(-k_depl * (1.0f - depl[nearest]) - lam * (float)hits[nearest]);
        s_near = nearest;
        s_fired = (msim > 0.85f) ? 1 : 0;
        gate_p[0] = g;
    }
    __syncthreads();

    int ptr = ptr_p[0];
    float nd = depl[n];
    int nh = hits[n];
    float nmsk = mk ? 1.0f : 0.0f;
    if (n == s_near && s_fired) { nd *= 0.5f; nh += 1; }
    if (n == ptr) { nd = 1.0f; nh = 0; nmsk = 1.0f; }
    out_depl[n] = nd;
    out_hits[n] = (float)nh;
    out_mask[n] = nmsk;
}

// Pass 2  (R14 form, unchanged — measured at 6.7 TB/s, at ceiling)
__global__ __launch_bounds__(256) void k_outbuf(const v4f* __restrict__ x4,
                                                v4f* __restrict__ o4,
                                                const v4f* __restrict__ buf4,
                                                const float* __restrict__ part2,
                                                const float* __restrict__ nm_p,
                                                v4f* __restrict__ ob4,
                                                const float* __restrict__ gate_p,
                                                const int* __restrict__ ptrp) {
    int t = threadIdx.x;
    if (blockIdx.x < 2048) {
        float g = gate_p[0];
        int base = blockIdx.x * 4096 + t;
        #pragma unroll
        for (int k = 0; k < 4; ++k) {
            int i0 = base + (4 * k + 0) * 256;
            int i1 = base + (4 * k + 1) * 256;
            int i2 = base + (4 * k + 2) * 256;
            int i3 = base + (4 * k + 3) * 256;
            v4f a0 = x4[i0];
            v4f a1 = x4[i1];
            v4f a2 = x4[i2];
            v4f a3 = x4[i3];
            v4f r0 = gelu4(a0, g);
            v4f r1 = gelu4(a1, g);
            v4f r2 = gelu4(a2, g);
            v4f r3 = gelu4(a3, g);
            __builtin_nontemporal_store(r0, &o4[i0]);
            __builtin_nontemporal_store(r1, &o4[i1]);
            __builtin_nontemporal_store(r2, &o4[i2]);
            __builtin_nontemporal_store(r3, &o4[i3]);
        }
    } else {
        int b2 = blockIdx.x - 2048;
        int ptr = ptrp[0];
        for (int k = 0; k < 16; ++k) {
            int i = b2 * 4096 + k * 256 + t;
            int row = i >> 8;
            v4f v;
            if (row == ptr) {
                int c4 = i & 255;
                float s0 = 0, s1 = 0, s2 = 0, s3 = 0;
                for (int r = 0; r < 16; ++r) {
                    v4f p = ((const v4f*)(part2 + r * DD))[c4];
                    s0 += p.x; s1 += p.y; s2 += p.z; s3 += p.w;
                }
                const float inv = 1.0f / 32768.0f;
                float den = fmaxf(nm_p[0], 1e-12f);
                v.x = s0 * inv / den;
                v.y = s1 * inv / den;
                v.z = s2 * inv / den;
                v.w = s3 * inv / den;
            } else {
                v = buf4[i];
            }
            ob4[i] = v;
        }
    }
}

extern "C" void kernel_launch(void* const* d_in, const int* in_sizes, int n_in,
                              void* d_out, int out_size, void* d_ws, size_t ws_size,
                              hipStream_t stream) {
    const float* x = (const float*)d_in[0];
    const float* log_k = (const float*)d_in[1];
    const float* log_lambda = (const float*)d_in[2];
    const float* buf = (const float*)d_in[3];
    const float* depl = (const float*)d_in[4];
    const int* hits = (const int*)d_in[5];
    const int* mask = (const int*)d_in[6];  // bool pushed as int32
    const int* ptr = (const int*)d_in[7];

    float* out = (float*)d_out;
    float* out_buf = out + 33554432;
    float* out_depl = out_buf + NN * DD;
    float* out_hits = out_depl + NN;
    float* out_mask = out_hits + NN;

    // small scratch in ws
    float* wsf = (float*)d_ws;
    float* part2 = wsf;              // 16*1024
    float* nm = wsf + 16384;
    float* gate = wsf + 16385;
    float* dot = wsf + 16400;        // 512
    float* sq = wsf + 16912;         // 512

    // big partial-sum scratch in the output region (4 MB), consumed before k_outbuf overwrites
    float* part = out;

    k_partial<<<dim3(PP), dim3(256), 0, stream>>>((const v4f*)x, (v4f*)part);
    k_reduce1<<<dim3(64), dim3(256), 0, stream>>>(part, part2);
    k_sims<<<dim3(NN), dim3(256), 0, stream>>>((const v4f*)buf, part2, dot, sq);
    k_state<<<dim3(1), dim3(512), 0, stream>>>(part2, dot, sq, depl, hits, mask,
                                               log_k, log_lambda, ptr,
                                               out_depl, out_hits, out_mask, gate, nm);
    k_outbuf<<<dim3(2080), dim3(256), 0, stream>>>((const v4f*)x, (v4f*)out,
                                                   (const v4f*)buf, part2, nm,
                                                   (v4f*)out_buf, gate, ptr);
}